// Round 3
// baseline (184.122 us; speedup 1.0000x reference)
//
#include <hip/hip_runtime.h>
#include <hip/hip_bf16.h>

typedef _Float16 half8 __attribute__((ext_vector_type(8)));
typedef float f32x4 __attribute__((ext_vector_type(4)));

#define B_ 8
#define U_ 1024
#define N_ 2048
#define DIN 128
#define H_ 4
#define HD 32
#define S_ 3072
#define LOG2E 1.44269504f

// ---------------- phase 1: projections + e-vectors + transposed f16 V ----------------
// users blocks: q_user -> vtB (V for news-direction), e_q_un -> eRowA, e_k_nu -> eColB
// news  blocks: k_news -> vtA (V for user-direction), e_k_un -> eColA, e_q_nu -> eRowB
// e layout: [b][h][r] head-major scalar (pre-scaled by log2 e).
__global__ __launch_bounds__(256) void p1_kernel(
    const float* __restrict__ uf, const float* __restrict__ nf,
    const float* __restrict__ Wu, const float* __restrict__ Wn,
    const float* __restrict__ a_un, const float* __restrict__ a_nu,
    _Float16* __restrict__ vtA, _Float16* __restrict__ vtB,
    float* __restrict__ eRowA, float* __restrict__ eColA,
    float* __restrict__ eRowB, float* __restrict__ eColB)
{
  __shared__ float fs[64][132];    // feature tile, padded
  __shared__ float WsT[32][132];   // W transposed [k][d], padded
  __shared__ float qt[32][65];     // q tile transposed [k][u]
  __shared__ float aAs[32], aBs[32];

  const int bid = blockIdx.x;
  const int tid = threadIdx.x;

  int b, rt, R;
  const float *feat, *W;
  _Float16* vt;
  float *eA, *eB;
  int aAoff, aBoff;
  const float *avA, *avB;
  if (bid < 128) {                       // users
    b = bid >> 4; rt = bid & 15; R = U_;
    feat = uf; W = Wu; vt = vtB;
    eA = eRowA; eB = eColB;
    avA = a_un; aAoff = 0;  avB = a_nu; aBoff = HD;
  } else {                               // news
    int t2 = bid - 128;
    b = t2 >> 5; rt = t2 & 31; R = N_;
    feat = nf; W = Wn; vt = vtA;
    eA = eColA; eB = eRowB;
    avA = a_un; aAoff = HD; avB = a_nu; aBoff = 0;
  }
  const int r0 = rt * 64;
  const float4* feat4 = (const float4*)(feat + ((size_t)b * R + r0) * DIN);
  #pragma unroll
  for (int i = 0; i < 8; ++i) {
    int f4 = tid + 256 * i;              // 0..2047 float4s of the 64x128 tile
    int row = f4 >> 5, c4 = f4 & 31;
    *(float4*)&fs[row][c4 * 4] = feat4[row * 32 + c4];
  }

  const int kk = tid & 15, uu = tid >> 4;    // compute mapping: 2 k-cols x 4 u-rows
  const int u2 = tid & 63, part = tid >> 6;  // store/e mapping
  float eAv[H_], eBv[H_];

  #pragma unroll
  for (int h = 0; h < H_; ++h) {
    __syncthreads();
    {
      const float4* W4 = (const float4*)(W + (size_t)h * DIN * HD);
      #pragma unroll
      for (int i = 0; i < 4; ++i) {
        int f4 = tid + 256 * i;          // 0..1023
        int d = f4 >> 3, kc = f4 & 7;
        float4 v = W4[f4];
        WsT[kc * 4 + 0][d] = v.x;
        WsT[kc * 4 + 1][d] = v.y;
        WsT[kc * 4 + 2][d] = v.z;
        WsT[kc * 4 + 3][d] = v.w;
      }
      if (tid < 32) {
        aAs[tid] = avA[h * 64 + aAoff + tid];
        aBs[tid] = avB[h * 64 + aBoff + tid];
      }
    }
    __syncthreads();
    {
      float acc0[4] = {0.f, 0.f, 0.f, 0.f}, acc1[4] = {0.f, 0.f, 0.f, 0.f};
      #pragma unroll 8
      for (int d = 0; d < DIN; d += 4) {
        float4 w0 = *(const float4*)&WsT[kk][d];
        float4 w1 = *(const float4*)&WsT[kk + 16][d];
        #pragma unroll
        for (int i = 0; i < 4; ++i) {
          float4 fv = *(const float4*)&fs[uu + 16 * i][d];
          acc0[i] = fmaf(fv.x, w0.x, acc0[i]); acc0[i] = fmaf(fv.y, w0.y, acc0[i]);
          acc0[i] = fmaf(fv.z, w0.z, acc0[i]); acc0[i] = fmaf(fv.w, w0.w, acc0[i]);
          acc1[i] = fmaf(fv.x, w1.x, acc1[i]); acc1[i] = fmaf(fv.y, w1.y, acc1[i]);
          acc1[i] = fmaf(fv.z, w1.z, acc1[i]); acc1[i] = fmaf(fv.w, w1.w, acc1[i]);
        }
      }
      #pragma unroll
      for (int i = 0; i < 4; ++i) {
        qt[kk][uu + 16 * i] = acc0[i];
        qt[kk + 16][uu + 16 * i] = acc1[i];
      }
    }
    __syncthreads();
    {
      size_t vtbase = ((size_t)(b * H_ + h) * HD) * R + r0;
      #pragma unroll
      for (int jj = 0; jj < 8; ++jj) {
        int krow = part * 8 + jj;
        vt[vtbase + (size_t)krow * R + u2] = (_Float16)qt[krow][u2];
      }
      float a_ = 0.f, b2_ = 0.f;
      #pragma unroll
      for (int k2 = 0; k2 < HD; ++k2) {
        float qv = qt[k2][u2];
        a_  = fmaf(qv, aAs[k2], a_);
        b2_ = fmaf(qv, aBs[k2], b2_);
      }
      eAv[h] = a_  * LOG2E;   // pre-scale by log2(e): exp(x) == exp2(x*LOG2E)
      eBv[h] = b2_ * LOG2E;
    }
  }
  if (part == 0) {
    #pragma unroll
    for (int h = 0; h < H_; ++h)
      eA[(size_t)(b * H_ + h) * R + r0 + u2] = eAv[h];
  } else if (part == 1) {
    #pragma unroll
    for (int h = 0; h < H_; ++h)
      eB[(size_t)(b * H_ + h) * R + r0 + u2] = eBv[h];
  }
}

// ---------------- phase 2: fused masked-softmax-weighted GEMM ----------------
// One 16-row tile per block, wave = head. Adjacency strip staged once as an
// LDS bitmask via __ballot (padded row stride -> conflict-free ds_read_u8).
// Per col-tile per wave: 1 byte mask + 2 float4 e + 2 half8 vt -> 3 MFMAs.
// num layout: [b][h][row][hd]; den: [b][h][row].
template<int RR, int CC, int ROFF, int COFF>
__global__ __launch_bounds__(256, 6) void p2t_kernel(
    const int* __restrict__ adj, const _Float16* __restrict__ vt,
    const float* __restrict__ eRow, const float* __restrict__ eCol,
    float* __restrict__ num, float* __restrict__ den)
{
  constexpr int CW64 = CC / 64;          // u64 words per mask row
  constexpr int PAD64 = CW64 + 1;        // +8B pad/row: banks hit 2r%32 -> conflict-free
  __shared__ unsigned long long maskU[16 * PAD64];

  const int tid = threadIdx.x;
  const int wave = tid >> 6, l = tid & 63;
  const int bid = blockIdx.x;
  constexpr int RT = RR / 16;
  const int b = bid / RT, rt = bid % RT;

  // ---- stage 16 x CC adjacency strip as bits (read once, coalesced) ----
  const int* adjBase = adj + (size_t)b * S_ * S_ + (size_t)(ROFF + rt * 16) * S_ + COFF;
  for (int i = 0; i < (16 * CW64) / 4; ++i) {
    int f = i * 4 + wave;
    int row = f / CW64, chunk = f % CW64;
    int av = adjBase[(size_t)row * S_ + chunk * 64 + l];
    unsigned long long m = __ballot(av != 0);
    if (l == 0) maskU[row * PAD64 + chunk] = m;
  }
  __syncthreads();

  const int h = wave;
  const int row16 = l & 15;
  const int cg = (l >> 4) << 3;          // A-frag K offset per lane group
  const int r = rt * 16 + row16;
  const float eq = eRow[(size_t)(b * H_ + h) * RR + r];
  const float* ecolH = eCol + (size_t)(b * H_ + h) * CC;
  const _Float16* vtb = vt + (size_t)(b * H_ + h) * HD * CC;
  const unsigned char* maskB = (const unsigned char*)maskU;
  const int mrowoff = row16 * (PAD64 * 8);

  f32x4 acc0 = {0.f, 0.f, 0.f, 0.f}, acc1 = {0.f, 0.f, 0.f, 0.f}, accd = {0.f, 0.f, 0.f, 0.f};
  half8 ones = {(_Float16)1.f, (_Float16)1.f, (_Float16)1.f, (_Float16)1.f,
                (_Float16)1.f, (_Float16)1.f, (_Float16)1.f, (_Float16)1.f};

  for (int t = 0; t < CC / 32; ++t) {
    const int cb = t * 32 + cg;
    unsigned int mb = maskB[mrowoff + (cb >> 3)];
    float4 e0 = *(const float4*)(ecolH + cb);
    float4 e1 = *(const float4*)(ecolH + cb + 4);
    float ecv[8] = {e0.x, e0.y, e0.z, e0.w, e1.x, e1.y, e1.z, e1.w};
    half8 w;
    #pragma unroll
    for (int j = 0; j < 8; ++j) {
      float s  = eq + ecv[j];                 // already log2e-scaled
      float ls = fmaxf(s, 0.2f * s);          // leaky (scale>0 commutes)
      ls = (mb & (1u << j)) ? ls : -1e9f;     // masked -> exp2 underflows to exact 0
      w[j] = (_Float16)exp2f(ls);
    }
    const half8 b0 = *(const half8*)(vtb + (size_t)row16 * CC + cb);
    const half8 b1 = *(const half8*)(vtb + (size_t)(row16 + 16) * CC + cb);
    acc0 = __builtin_amdgcn_mfma_f32_16x16x32_f16(w, b0, acc0, 0, 0, 0);
    acc1 = __builtin_amdgcn_mfma_f32_16x16x32_f16(w, b1, acc1, 0, 0, 0);
    accd = __builtin_amdgcn_mfma_f32_16x16x32_f16(w, ones, accd, 0, 0, 0);
  }

  const int colk = row16;
  const int rowbase = rt * 16 + ((l >> 4) << 2);
  #pragma unroll
  for (int q = 0; q < 4; ++q) {
    int orow = rowbase + q;                  // C layout: col=l&15, row=(l>>4)*4+q
    size_t o = ((size_t)(b * H_ + h) * RR + orow) * 32 + colk;
    num[o] = acc0[q];
    num[o + 16] = acc1[q];
    if (colk == 0) den[(size_t)(b * H_ + h) * RR + orow] = accd[q];
  }
}

// ---------------- phase 3: divide, bias, relu (1:1 coalesced) ----------------
__global__ __launch_bounds__(256) void p3_kernel(
    const float* __restrict__ numA, const float* __restrict__ denA,
    const float* __restrict__ numB, const float* __restrict__ denB,
    const float* __restrict__ bu, const float* __restrict__ bn,
    float* __restrict__ out)
{
  int idx = blockIdx.x * 256 + threadIdx.x;
  const int nU = B_ * U_ * 128;                    // 1048576
  if (idx < nU) {
    float v = numA[idx] / denA[idx >> 5] + bu[idx & 127];
    out[idx] = v > 0.f ? v : 0.f;
  } else {
    int i2 = idx - nU;
    float v = numB[i2] / denB[i2 >> 5] + bn[i2 & 127];
    out[idx] = v > 0.f ? v : 0.f;
  }
}

extern "C" void kernel_launch(void* const* d_in, const int* in_sizes, int n_in,
                              void* d_out, int out_size, void* d_ws, size_t ws_size,
                              hipStream_t stream) {
  const float* uf  = (const float*)d_in[0];
  const float* nf  = (const float*)d_in[1];
  const int*   adj = (const int*)d_in[2];
  const float* Wu  = (const float*)d_in[3];
  const float* Wn  = (const float*)d_in[4];
  const float* aun = (const float*)d_in[5];
  const float* anu = (const float*)d_in[6];
  const float* bu  = (const float*)d_in[7];
  const float* bn  = (const float*)d_in[8];

  char* ws = (char*)d_ws;
  size_t off = 0;
  _Float16* vtA = (_Float16*)(ws + off); off += (size_t)B_ * H_ * HD * N_ * 2;  // 4 MB
  _Float16* vtB = (_Float16*)(ws + off); off += (size_t)B_ * H_ * HD * U_ * 2;  // 2 MB
  float* eRowA = (float*)(ws + off); off += (size_t)B_ * H_ * U_ * 4;
  float* eColA = (float*)(ws + off); off += (size_t)B_ * H_ * N_ * 4;
  float* eRowB = (float*)(ws + off); off += (size_t)B_ * H_ * N_ * 4;
  float* eColB = (float*)(ws + off); off += (size_t)B_ * H_ * U_ * 4;
  float* numA = (float*)(ws + off); off += (size_t)B_ * U_ * 128 * 4;           // 4 MB
  float* denA = (float*)(ws + off); off += (size_t)B_ * U_ * H_ * 4;
  float* numB = (float*)(ws + off); off += (size_t)B_ * N_ * 128 * 4;           // 8 MB
  float* denB = (float*)(ws + off); off += (size_t)B_ * N_ * H_ * 4;
  (void)off; (void)ws_size; (void)in_sizes; (void)n_in; (void)out_size;        // ~19.2 MB total

  p1_kernel<<<384, 256, 0, stream>>>(uf, nf, Wu, Wn, aun, anu,
                                     vtA, vtB, eRowA, eColA, eRowB, eColB);
  // direction A: rows=users (R=1024, row-offset 0, col-offset U)
  p2t_kernel<U_, N_, 0, U_><<<8 * (U_ / 16), 256, 0, stream>>>(
      adj, vtA, eRowA, eColA, numA, denA);
  // direction B: rows=news (R=2048, row-offset U, col-offset 0)
  p2t_kernel<N_, U_, U_, 0><<<8 * (N_ / 16), 256, 0, stream>>>(
      adj, vtB, eRowB, eColB, numB, denB);
  p3_kernel<<<12288, 256, 0, stream>>>(numA, denA, numB, denB, bu, bn, (float*)d_out);
}

// Round 5
// 144.790 us; speedup vs baseline: 1.2716x; 1.2716x over previous
//
#include <hip/hip_runtime.h>
#include <hip/hip_bf16.h>

typedef _Float16 half8 __attribute__((ext_vector_type(8)));
typedef __fp16 fp16x2 __attribute__((ext_vector_type(2)));
typedef float f32x4 __attribute__((ext_vector_type(4)));

#define B_ 8
#define U_ 1024
#define N_ 2048
#define DIN 128
#define H_ 4
#define HD 32
#define S_ 3072
#define LOG2E 1.44269504f

// ---------------- phase 1: projections + e-vectors + transposed f16 V ----------------
// users blocks: q_user -> vtB (V for news-direction), e_q_un -> eRowA, e_k_nu -> eColB
// news  blocks: k_news -> vtA (V for user-direction), e_k_un -> eColA, e_q_nu -> eRowB
// e layout: [b][h][r] head-major scalar (pre-scaled by log2 e).
__global__ __launch_bounds__(256) void p1_kernel(
    const float* __restrict__ uf, const float* __restrict__ nf,
    const float* __restrict__ Wu, const float* __restrict__ Wn,
    const float* __restrict__ a_un, const float* __restrict__ a_nu,
    _Float16* __restrict__ vtA, _Float16* __restrict__ vtB,
    float* __restrict__ eRowA, float* __restrict__ eColA,
    float* __restrict__ eRowB, float* __restrict__ eColB)
{
  __shared__ float fs[64][132];    // feature tile, padded
  __shared__ float WsT[32][132];   // W transposed [k][d], padded
  __shared__ float qt[32][65];     // q tile transposed [k][u]
  __shared__ float aAs[32], aBs[32];

  const int bid = blockIdx.x;
  const int tid = threadIdx.x;

  int b, rt, R;
  const float *feat, *W;
  _Float16* vt;
  float *eA, *eB;
  int aAoff, aBoff;
  const float *avA, *avB;
  if (bid < 128) {                       // users
    b = bid >> 4; rt = bid & 15; R = U_;
    feat = uf; W = Wu; vt = vtB;
    eA = eRowA; eB = eColB;
    avA = a_un; aAoff = 0;  avB = a_nu; aBoff = HD;
  } else {                               // news
    int t2 = bid - 128;
    b = t2 >> 5; rt = t2 & 31; R = N_;
    feat = nf; W = Wn; vt = vtA;
    eA = eColA; eB = eRowB;
    avA = a_un; aAoff = HD; avB = a_nu; aBoff = 0;
  }
  const int r0 = rt * 64;
  const float4* feat4 = (const float4*)(feat + ((size_t)b * R + r0) * DIN);
  #pragma unroll
  for (int i = 0; i < 8; ++i) {
    int f4 = tid + 256 * i;              // 0..2047 float4s of the 64x128 tile
    int row = f4 >> 5, c4 = f4 & 31;
    *(float4*)&fs[row][c4 * 4] = feat4[row * 32 + c4];
  }

  const int kk = tid & 15, uu = tid >> 4;    // compute mapping: 2 k-cols x 4 u-rows
  const int u2 = tid & 63, part = tid >> 6;  // store/e mapping
  float eAv[H_], eBv[H_];

  #pragma unroll
  for (int h = 0; h < H_; ++h) {
    __syncthreads();
    {
      const float4* W4 = (const float4*)(W + (size_t)h * DIN * HD);
      #pragma unroll
      for (int i = 0; i < 4; ++i) {
        int f4 = tid + 256 * i;          // 0..1023
        int d = f4 >> 3, kc = f4 & 7;
        float4 v = W4[f4];
        WsT[kc * 4 + 0][d] = v.x;
        WsT[kc * 4 + 1][d] = v.y;
        WsT[kc * 4 + 2][d] = v.z;
        WsT[kc * 4 + 3][d] = v.w;
      }
      if (tid < 32) {
        aAs[tid] = avA[h * 64 + aAoff + tid];
        aBs[tid] = avB[h * 64 + aBoff + tid];
      }
    }
    __syncthreads();
    {
      float acc0[4] = {0.f, 0.f, 0.f, 0.f}, acc1[4] = {0.f, 0.f, 0.f, 0.f};
      #pragma unroll 8
      for (int d = 0; d < DIN; d += 4) {
        float4 w0 = *(const float4*)&WsT[kk][d];
        float4 w1 = *(const float4*)&WsT[kk + 16][d];
        #pragma unroll
        for (int i = 0; i < 4; ++i) {
          float4 fv = *(const float4*)&fs[uu + 16 * i][d];
          acc0[i] = fmaf(fv.x, w0.x, acc0[i]); acc0[i] = fmaf(fv.y, w0.y, acc0[i]);
          acc0[i] = fmaf(fv.z, w0.z, acc0[i]); acc0[i] = fmaf(fv.w, w0.w, acc0[i]);
          acc1[i] = fmaf(fv.x, w1.x, acc1[i]); acc1[i] = fmaf(fv.y, w1.y, acc1[i]);
          acc1[i] = fmaf(fv.z, w1.z, acc1[i]); acc1[i] = fmaf(fv.w, w1.w, acc1[i]);
        }
      }
      #pragma unroll
      for (int i = 0; i < 4; ++i) {
        qt[kk][uu + 16 * i] = acc0[i];
        qt[kk + 16][uu + 16 * i] = acc1[i];
      }
    }
    __syncthreads();
    {
      size_t vtbase = ((size_t)(b * H_ + h) * HD) * R + r0;
      #pragma unroll
      for (int jj = 0; jj < 8; ++jj) {
        int krow = part * 8 + jj;
        vt[vtbase + (size_t)krow * R + u2] = (_Float16)qt[krow][u2];
      }
      float a_ = 0.f, b2_ = 0.f;
      #pragma unroll
      for (int k2 = 0; k2 < HD; ++k2) {
        float qv = qt[k2][u2];
        a_  = fmaf(qv, aAs[k2], a_);
        b2_ = fmaf(qv, aBs[k2], b2_);
      }
      eAv[h] = a_  * LOG2E;   // pre-scale by log2(e): exp(x) == exp2(x*LOG2E)
      eBv[h] = b2_ * LOG2E;
    }
  }
  if (part == 0) {
    #pragma unroll
    for (int h = 0; h < H_; ++h)
      eA[(size_t)(b * H_ + h) * R + r0 + u2] = eAv[h];
  } else if (part == 1) {
    #pragma unroll
    for (int h = 0; h < H_; ++h)
      eB[(size_t)(b * H_ + h) * R + r0 + u2] = eBv[h];
  }
}

// ---------------- phase 2 core: fused masked-softmax-weighted GEMM ----------------
// One 16-row tile per block, wave = head. Adjacency strip staged once as an
// LDS bitmask via __ballot. Per col-tile per wave: 1 broadcast ds_read_b32 +
// 2 float4 e (broadcast) + 2 half8 vt -> 3 MFMAs (num x2 + ones-B den).
// num layout: [b][h][row][hd]; den: [b][h][row].
template<int RR, int CC, int ROFF, int COFF, int PAD64>
__device__ __forceinline__ void p2_core(
    int b, int rt, int wave, int l,
    const int* __restrict__ adj, const _Float16* __restrict__ vt,
    const float* __restrict__ eRow, const float* __restrict__ eCol,
    float* __restrict__ num, float* __restrict__ den,
    unsigned long long* maskU)
{
  constexpr int CW64 = CC / 64;          // u64 words per mask row

  // ---- stage 16 x CC adjacency strip as bits (read once, coalesced) ----
  const int* adjBase = adj + (size_t)b * S_ * S_ + (size_t)(ROFF + rt * 16) * S_ + COFF;
  #pragma unroll 4
  for (int i = 0; i < (16 * CW64) / 4; ++i) {
    int f = i * 4 + wave;
    int row = f / CW64, chunk = f % CW64;
    int av = adjBase[(size_t)row * S_ + chunk * 64 + l];
    unsigned long long m = __ballot(av != 0);
    if (l == 0) maskU[row * PAD64 + chunk] = m;
  }
  __syncthreads();

  const int h = wave;
  const int row16 = l & 15;
  const int cg = (l >> 4) << 3;          // per-lane-group K offset within 32-col tile
  const int r = rt * 16 + row16;
  const float eq = eRow[(size_t)(b * H_ + h) * RR + r];
  const float* ecolH = eCol + (size_t)(b * H_ + h) * CC;
  const _Float16* vtb = vt + (size_t)(b * H_ + h) * HD * CC;
  const unsigned int* maskW = (const unsigned int*)maskU;
  const int mrow = row16 * (PAD64 * 2);  // u32 words per row (padded)

  f32x4 acc0 = {0.f, 0.f, 0.f, 0.f}, acc1 = {0.f, 0.f, 0.f, 0.f}, accd = {0.f, 0.f, 0.f, 0.f};
  half8 ones = {(_Float16)1.f, (_Float16)1.f, (_Float16)1.f, (_Float16)1.f,
                (_Float16)1.f, (_Float16)1.f, (_Float16)1.f, (_Float16)1.f};

  #pragma unroll 4
  for (int t = 0; t < CC / 32; ++t) {
    const int cb = t * 32 + cg;
    unsigned int mb = maskW[mrow + t] >> cg;     // same-word broadcast across groups
    float4 e0 = *(const float4*)(ecolH + cb);
    float4 e1 = *(const float4*)(ecolH + cb + 4);
    float ecv[8] = {e0.x, e0.y, e0.z, e0.w, e1.x, e1.y, e1.z, e1.w};
    float wv[8];
    #pragma unroll
    for (int j = 0; j < 8; ++j) {
      float s  = eq + ecv[j];                 // already log2e-scaled
      float ls = fmaxf(s, 0.2f * s);          // leaky (positive scale commutes)
      ls = (mb & (1u << j)) ? ls : -1e9f;     // masked -> exp2 underflows to exact 0
      wv[j] = exp2f(ls);
    }
    union { fp16x2 h2[4]; half8 h8; } uw;
    #pragma unroll
    for (int j = 0; j < 4; ++j)
      uw.h2[j] = __builtin_amdgcn_cvt_pkrtz(wv[2 * j], wv[2 * j + 1]);
    half8 w = uw.h8;
    const half8 b0 = *(const half8*)(vtb + (size_t)row16 * CC + cb);
    const half8 b1 = *(const half8*)(vtb + (size_t)(row16 + 16) * CC + cb);
    acc0 = __builtin_amdgcn_mfma_f32_16x16x32_f16(w, b0, acc0, 0, 0, 0);
    acc1 = __builtin_amdgcn_mfma_f32_16x16x32_f16(w, b1, acc1, 0, 0, 0);
    accd = __builtin_amdgcn_mfma_f32_16x16x32_f16(w, ones, accd, 0, 0, 0);
  }

  const int colk = row16;
  const int rowbase = rt * 16 + ((l >> 4) << 2);
  #pragma unroll
  for (int q = 0; q < 4; ++q) {
    int orow = rowbase + q;                  // C layout: col=l&15, row=(l>>4)*4+q
    size_t o = ((size_t)(b * H_ + h) * RR + orow) * 32 + colk;
    num[o] = acc0[q];
    num[o + 16] = acc1[q];
    if (colk == 0) den[(size_t)(b * H_ + h) * RR + orow] = accd[q];
  }
}

// Both directions in ONE grid: bid 0..511 = direction A (rows=users),
// bid 512..1535 = direction B (rows=news). Whole-block-uniform branch.
__global__ __launch_bounds__(256, 6) void p2_kernel(
    const int* __restrict__ adj,
    const _Float16* __restrict__ vtA, const _Float16* __restrict__ vtB,
    const float* __restrict__ eRowA, const float* __restrict__ eColA,
    const float* __restrict__ eRowB, const float* __restrict__ eColB,
    float* __restrict__ numA, float* __restrict__ denA,
    float* __restrict__ numB, float* __restrict__ denB)
{
  __shared__ unsigned long long maskU[16 * 33];   // max of the two instantiations
  const int tid = threadIdx.x;
  const int wave = tid >> 6, l = tid & 63;
  const int bid = blockIdx.x;
  if (bid < B_ * (U_ / 16)) {
    const int b = bid >> 6, rt = bid & 63;
    p2_core<U_, N_, 0, U_, 33>(b, rt, wave, l, adj, vtA, eRowA, eColA, numA, denA, maskU);
  } else {
    const int t2 = bid - B_ * (U_ / 16);
    const int b = t2 >> 7, rt = t2 & 127;
    p2_core<N_, U_, U_, 0, 17>(b, rt, wave, l, adj, vtB, eRowB, eColB, numB, denB, maskU);
  }
}

// ---------------- phase 3: divide, bias, relu (1:1 coalesced) ----------------
__global__ __launch_bounds__(256) void p3_kernel(
    const float* __restrict__ numA, const float* __restrict__ denA,
    const float* __restrict__ numB, const float* __restrict__ denB,
    const float* __restrict__ bu, const float* __restrict__ bn,
    float* __restrict__ out)
{
  int idx = blockIdx.x * 256 + threadIdx.x;
  const int nU = B_ * U_ * 128;                    // 1048576
  if (idx < nU) {
    float v = numA[idx] / denA[idx >> 5] + bu[idx & 127];
    out[idx] = v > 0.f ? v : 0.f;
  } else {
    int i2 = idx - nU;
    float v = numB[i2] / denB[i2 >> 5] + bn[i2 & 127];
    out[idx] = v > 0.f ? v : 0.f;
  }
}

extern "C" void kernel_launch(void* const* d_in, const int* in_sizes, int n_in,
                              void* d_out, int out_size, void* d_ws, size_t ws_size,
                              hipStream_t stream) {
  const float* uf  = (const float*)d_in[0];
  const float* nf  = (const float*)d_in[1];
  const int*   adj = (const int*)d_in[2];
  const float* Wu  = (const float*)d_in[3];
  const float* Wn  = (const float*)d_in[4];
  const float* aun = (const float*)d_in[5];
  const float* anu = (const float*)d_in[6];
  const float* bu  = (const float*)d_in[7];
  const float* bn  = (const float*)d_in[8];

  char* ws = (char*)d_ws;
  size_t off = 0;
  _Float16* vtA = (_Float16*)(ws + off); off += (size_t)B_ * H_ * HD * N_ * 2;  // 4 MB
  _Float16* vtB = (_Float16*)(ws + off); off += (size_t)B_ * H_ * HD * U_ * 2;  // 2 MB
  float* eRowA = (float*)(ws + off); off += (size_t)B_ * H_ * U_ * 4;
  float* eColA = (float*)(ws + off); off += (size_t)B_ * H_ * N_ * 4;
  float* eRowB = (float*)(ws + off); off += (size_t)B_ * H_ * N_ * 4;
  float* eColB = (float*)(ws + off); off += (size_t)B_ * H_ * U_ * 4;
  float* numA = (float*)(ws + off); off += (size_t)B_ * U_ * 128 * 4;           // 4 MB
  float* denA = (float*)(ws + off); off += (size_t)B_ * U_ * H_ * 4;
  float* numB = (float*)(ws + off); off += (size_t)B_ * N_ * 128 * 4;           // 8 MB
  float* denB = (float*)(ws + off); off += (size_t)B_ * N_ * H_ * 4;
  (void)off; (void)ws_size; (void)in_sizes; (void)n_in; (void)out_size;        // ~19.2 MB total

  p1_kernel<<<384, 256, 0, stream>>>(uf, nf, Wu, Wn, aun, anu,
                                     vtA, vtB, eRowA, eColA, eRowB, eColB);
  p2_kernel<<<B_ * (U_ / 16) + B_ * (N_ / 16), 256, 0, stream>>>(
      adj, vtA, vtB, eRowA, eColA, eRowB, eColB, numA, denA, numB, denB);
  p3_kernel<<<12288, 256, 0, stream>>>(numA, denA, numB, denB, bu, bn, (float*)d_out);
}

// Round 6
// 139.942 us; speedup vs baseline: 1.3157x; 1.0346x over previous
//
#include <hip/hip_runtime.h>
#include <hip/hip_bf16.h>

typedef _Float16 half8 __attribute__((ext_vector_type(8)));
typedef __fp16 fp16x2 __attribute__((ext_vector_type(2)));
typedef float f32x4 __attribute__((ext_vector_type(4)));

#define B_ 8
#define U_ 1024
#define N_ 2048
#define DIN 128
#define H_ 4
#define HD 32
#define S_ 3072
#define LOG2E 1.44269504f

// ---------------- phase 1: projections + e-vectors + tiled f16 V ----------------
// users blocks: q_user -> vtB (V for news-direction), e_q_un -> eRowA, e_k_nu -> eColB
// news  blocks: k_news -> vtA (V for user-direction), e_k_un -> eColA, e_q_nu -> eRowB
// e layout: [b][h][r] (pre-scaled by log2 e).
// vt layout: [b][h][tile=c/32][hd][kk=c%32]  (2KB blocks; p2 B-frag reads are contiguous)
__global__ __launch_bounds__(256) void p1_kernel(
    const float* __restrict__ uf, const float* __restrict__ nf,
    const float* __restrict__ Wu, const float* __restrict__ Wn,
    const float* __restrict__ a_un, const float* __restrict__ a_nu,
    _Float16* __restrict__ vtA, _Float16* __restrict__ vtB,
    float* __restrict__ eRowA, float* __restrict__ eColA,
    float* __restrict__ eRowB, float* __restrict__ eColB)
{
  __shared__ float fs[64][132];    // feature tile, padded
  __shared__ float WsT[32][132];   // W transposed [k][d], padded
  __shared__ float qt[32][65];     // q tile transposed [k][u]
  __shared__ float aAs[32], aBs[32];

  const int bid = blockIdx.x;
  const int tid = threadIdx.x;

  int b, rt, R;
  const float *feat, *W;
  _Float16* vt;
  float *eA, *eB;
  int aAoff, aBoff;
  const float *avA, *avB;
  if (bid < 128) {                       // users
    b = bid >> 4; rt = bid & 15; R = U_;
    feat = uf; W = Wu; vt = vtB;
    eA = eRowA; eB = eColB;
    avA = a_un; aAoff = 0;  avB = a_nu; aBoff = HD;
  } else {                               // news
    int t2 = bid - 128;
    b = t2 >> 5; rt = t2 & 31; R = N_;
    feat = nf; W = Wn; vt = vtA;
    eA = eColA; eB = eRowB;
    avA = a_un; aAoff = HD; avB = a_nu; aBoff = 0;
  }
  const int r0 = rt * 64;
  const float4* feat4 = (const float4*)(feat + ((size_t)b * R + r0) * DIN);
  #pragma unroll
  for (int i = 0; i < 8; ++i) {
    int f4 = tid + 256 * i;              // 0..2047 float4s of the 64x128 tile
    int row = f4 >> 5, c4 = f4 & 31;
    *(float4*)&fs[row][c4 * 4] = feat4[row * 32 + c4];
  }

  const int kk = tid & 15, uu = tid >> 4;    // compute mapping: 2 k-cols x 4 u-rows
  const int u2 = tid & 63, part = tid >> 6;  // store/e mapping
  float eAv[H_], eBv[H_];

  #pragma unroll
  for (int h = 0; h < H_; ++h) {
    __syncthreads();
    {
      const float4* W4 = (const float4*)(W + (size_t)h * DIN * HD);
      #pragma unroll
      for (int i = 0; i < 4; ++i) {
        int f4 = tid + 256 * i;          // 0..1023
        int d = f4 >> 3, kc = f4 & 7;
        float4 v = W4[f4];
        WsT[kc * 4 + 0][d] = v.x;
        WsT[kc * 4 + 1][d] = v.y;
        WsT[kc * 4 + 2][d] = v.z;
        WsT[kc * 4 + 3][d] = v.w;
      }
      if (tid < 32) {
        aAs[tid] = avA[h * 64 + aAoff + tid];
        aBs[tid] = avB[h * 64 + aBoff + tid];
      }
    }
    __syncthreads();
    {
      float acc0[4] = {0.f, 0.f, 0.f, 0.f}, acc1[4] = {0.f, 0.f, 0.f, 0.f};
      #pragma unroll 8
      for (int d = 0; d < DIN; d += 4) {
        float4 w0 = *(const float4*)&WsT[kk][d];
        float4 w1 = *(const float4*)&WsT[kk + 16][d];
        #pragma unroll
        for (int i = 0; i < 4; ++i) {
          float4 fv = *(const float4*)&fs[uu + 16 * i][d];
          acc0[i] = fmaf(fv.x, w0.x, acc0[i]); acc0[i] = fmaf(fv.y, w0.y, acc0[i]);
          acc0[i] = fmaf(fv.z, w0.z, acc0[i]); acc0[i] = fmaf(fv.w, w0.w, acc0[i]);
          acc1[i] = fmaf(fv.x, w1.x, acc1[i]); acc1[i] = fmaf(fv.y, w1.y, acc1[i]);
          acc1[i] = fmaf(fv.z, w1.z, acc1[i]); acc1[i] = fmaf(fv.w, w1.w, acc1[i]);
        }
      }
      #pragma unroll
      for (int i = 0; i < 4; ++i) {
        qt[kk][uu + 16 * i] = acc0[i];
        qt[kk + 16][uu + 16 * i] = acc1[i];
      }
    }
    __syncthreads();
    {
      // vt store: c = r0+u2 -> tile (r0+u2)>>5, kk=(r0+u2)&31; element [tile][krow][kk]
      size_t vtbase = (size_t)(b * H_ + h) * (R * HD)
                    + (size_t)((r0 >> 5) + (u2 >> 5)) * (HD * 32) + (u2 & 31);
      #pragma unroll
      for (int jj = 0; jj < 8; ++jj) {
        int krow = part * 8 + jj;
        vt[vtbase + krow * 32] = (_Float16)qt[krow][u2];
      }
      float a_ = 0.f, b2_ = 0.f;
      #pragma unroll
      for (int k2 = 0; k2 < HD; ++k2) {
        float qv = qt[k2][u2];
        a_  = fmaf(qv, aAs[k2], a_);
        b2_ = fmaf(qv, aBs[k2], b2_);
      }
      eAv[h] = a_  * LOG2E;   // pre-scale by log2(e): exp(x) == exp2(x*LOG2E)
      eBv[h] = b2_ * LOG2E;
    }
  }
  if (part == 0) {
    #pragma unroll
    for (int h = 0; h < H_; ++h)
      eA[(size_t)(b * H_ + h) * R + r0 + u2] = eAv[h];
  } else if (part == 1) {
    #pragma unroll
    for (int h = 0; h < H_; ++h)
      eB[(size_t)(b * H_ + h) * R + r0 + u2] = eBv[h];
  }
}

// ---------------- phase 2 core: fused masked-softmax-weighted GEMM + epilogue ----------------
// One 16-row tile per block, wave = head. Adjacency strip staged once as an
// LDS bitmask via __ballot. Per col-tile per wave: 1 broadcast ds_read_b32 +
// 2 float4 e (broadcast) + 2 contiguous half8 vt -> 3 MFMAs (num x2 + ones-B den).
// Epilogue: accd[q] holds den[row] in every lane -> divide+bias+relu -> out directly.
template<int RR, int CC, int ROFF, int COFF, int PAD64>
__device__ __forceinline__ void p2_core(
    int b, int rt, int wave, int l,
    const int* __restrict__ adj, const _Float16* __restrict__ vt,
    const float* __restrict__ eRow, const float* __restrict__ eCol,
    const float* __restrict__ bias, float* __restrict__ out,
    unsigned long long* maskU)
{
  constexpr int CW64 = CC / 64;          // u64 words per mask row

  // ---- stage 16 x CC adjacency strip as bits (read once, coalesced) ----
  const int* adjBase = adj + (size_t)b * S_ * S_ + (size_t)(ROFF + rt * 16) * S_ + COFF;
  #pragma unroll 4
  for (int i = 0; i < (16 * CW64) / 4; ++i) {
    int f = i * 4 + wave;
    int row = f / CW64, chunk = f % CW64;
    int av = adjBase[(size_t)row * S_ + chunk * 64 + l];
    unsigned long long m = __ballot(av != 0);
    if (l == 0) maskU[row * PAD64 + chunk] = m;
  }
  __syncthreads();

  const int h = wave;
  const int row16 = l & 15;
  const int cg = (l >> 4) << 3;          // per-lane-group K offset within 32-col tile
  const int r = rt * 16 + row16;
  const float eq = eRow[(size_t)(b * H_ + h) * RR + r];
  const float* ecolH = eCol + (size_t)(b * H_ + h) * CC;
  const _Float16* vtb = vt + (size_t)(b * H_ + h) * (CC * HD);
  const unsigned int* maskW = (const unsigned int*)maskU;
  const int mrow = row16 * (PAD64 * 2);  // u32 words per row (padded)

  f32x4 acc0 = {0.f, 0.f, 0.f, 0.f}, acc1 = {0.f, 0.f, 0.f, 0.f}, accd = {0.f, 0.f, 0.f, 0.f};
  half8 ones = {(_Float16)1.f, (_Float16)1.f, (_Float16)1.f, (_Float16)1.f,
                (_Float16)1.f, (_Float16)1.f, (_Float16)1.f, (_Float16)1.f};

  #pragma unroll 4
  for (int t = 0; t < CC / 32; ++t) {
    const int cb = t * 32 + cg;
    unsigned int mb = maskW[mrow + t] >> cg;     // same-word broadcast across groups
    float4 e0 = *(const float4*)(ecolH + cb);
    float4 e1 = *(const float4*)(ecolH + cb + 4);
    float ecv[8] = {e0.x, e0.y, e0.z, e0.w, e1.x, e1.y, e1.z, e1.w};
    float wv[8];
    #pragma unroll
    for (int j = 0; j < 8; ++j) {
      float s  = eq + ecv[j];                 // already log2e-scaled
      float ls = fmaxf(s, 0.2f * s);          // leaky (positive scale commutes)
      ls = (mb & (1u << j)) ? ls : -1e9f;     // masked -> exp2 underflows to exact 0
      wv[j] = exp2f(ls);
    }
    union { fp16x2 h2[4]; half8 h8; } uw;
    #pragma unroll
    for (int j = 0; j < 4; ++j)
      uw.h2[j] = __builtin_amdgcn_cvt_pkrtz(wv[2 * j], wv[2 * j + 1]);
    half8 w = uw.h8;
    // tile-interleaved V: [t][hd][kk] -> wave reads 2x1KB contiguous
    const half8 b0 = *(const half8*)(vtb + t * (HD * 32) + row16 * 32 + cg);
    const half8 b1 = *(const half8*)(vtb + t * (HD * 32) + (row16 + 16) * 32 + cg);
    acc0 = __builtin_amdgcn_mfma_f32_16x16x32_f16(w, b0, acc0, 0, 0, 0);
    acc1 = __builtin_amdgcn_mfma_f32_16x16x32_f16(w, b1, acc1, 0, 0, 0);
    accd = __builtin_amdgcn_mfma_f32_16x16x32_f16(w, ones, accd, 0, 0, 0);
  }

  // ---- fused epilogue: divide, bias, relu, store ----
  const int colk = row16;
  const int rowbase = rt * 16 + ((l >> 4) << 2);
  #pragma unroll
  for (int q = 0; q < 4; ++q) {
    int orow = rowbase + q;                  // C layout: col=l&15, row=(l>>4)*4+q
    size_t o = ((size_t)(b * H_ + h) * RR + orow) * 32 + colk;
    float den = accd[q];                     // den[row] replicated across cols
    float v0 = acc0[q] / den + bias[q * 32 + colk];
    float v1 = acc1[q] / den + bias[q * 32 + colk + 16];
    out[o]      = v0 > 0.f ? v0 : 0.f;
    out[o + 16] = v1 > 0.f ? v1 : 0.f;
  }
}

// Both directions in ONE grid: bid 0..511 = direction A (rows=users),
// bid 512..1535 = direction B (rows=news). Whole-block-uniform branch.
__global__ __launch_bounds__(256, 6) void p2_kernel(
    const int* __restrict__ adj,
    const _Float16* __restrict__ vtA, const _Float16* __restrict__ vtB,
    const float* __restrict__ eRowA, const float* __restrict__ eColA,
    const float* __restrict__ eRowB, const float* __restrict__ eColB,
    const float* __restrict__ bu, const float* __restrict__ bn,
    float* __restrict__ out)
{
  __shared__ unsigned long long maskU[16 * 33];   // max of the two instantiations
  const int tid = threadIdx.x;
  const int wave = tid >> 6, l = tid & 63;
  const int bid = blockIdx.x;
  if (bid < B_ * (U_ / 16)) {
    const int b = bid >> 6, rt = bid & 63;
    p2_core<U_, N_, 0, U_, 33>(b, rt, wave, l, adj, vtA, eRowA, eColA, bu,
                               out, maskU);
  } else {
    const int t2 = bid - B_ * (U_ / 16);
    const int b = t2 >> 7, rt = t2 & 127;
    p2_core<N_, U_, U_, 0, 17>(b, rt, wave, l, adj, vtB, eRowB, eColB, bn,
                               out + (size_t)B_ * U_ * 128, maskU);
  }
}

extern "C" void kernel_launch(void* const* d_in, const int* in_sizes, int n_in,
                              void* d_out, int out_size, void* d_ws, size_t ws_size,
                              hipStream_t stream) {
  const float* uf  = (const float*)d_in[0];
  const float* nf  = (const float*)d_in[1];
  const int*   adj = (const int*)d_in[2];
  const float* Wu  = (const float*)d_in[3];
  const float* Wn  = (const float*)d_in[4];
  const float* aun = (const float*)d_in[5];
  const float* anu = (const float*)d_in[6];
  const float* bu  = (const float*)d_in[7];
  const float* bn  = (const float*)d_in[8];

  char* ws = (char*)d_ws;
  size_t off = 0;
  _Float16* vtA = (_Float16*)(ws + off); off += (size_t)B_ * H_ * HD * N_ * 2;  // 4 MB
  _Float16* vtB = (_Float16*)(ws + off); off += (size_t)B_ * H_ * HD * U_ * 2;  // 2 MB
  float* eRowA = (float*)(ws + off); off += (size_t)B_ * H_ * U_ * 4;
  float* eColA = (float*)(ws + off); off += (size_t)B_ * H_ * N_ * 4;
  float* eRowB = (float*)(ws + off); off += (size_t)B_ * H_ * N_ * 4;
  float* eColB = (float*)(ws + off); off += (size_t)B_ * H_ * U_ * 4;
  (void)off; (void)ws_size; (void)in_sizes; (void)n_in; (void)out_size;        // ~7.7 MB total

  p1_kernel<<<384, 256, 0, stream>>>(uf, nf, Wu, Wn, aun, anu,
                                     vtA, vtB, eRowA, eColA, eRowB, eColB);
  p2_kernel<<<B_ * (U_ / 16) + B_ * (N_ / 16), 256, 0, stream>>>(
      adj, vtA, vtB, eRowA, eColA, eRowB, eColB, bu, bn, (float*)d_out);
}

// Round 7
// 121.626 us; speedup vs baseline: 1.5138x; 1.1506x over previous
//
#include <hip/hip_runtime.h>
#include <hip/hip_bf16.h>

typedef _Float16 half8 __attribute__((ext_vector_type(8)));
typedef __fp16 fp16x2 __attribute__((ext_vector_type(2)));
typedef float f32x4 __attribute__((ext_vector_type(4)));

#define B_ 8
#define U_ 1024
#define N_ 2048
#define DIN 128
#define H_ 4
#define HD 32
#define S_ 3072
#define LOG2E 1.44269504f

// ---------------- phase 1: projections + e-vectors + tiled f16 V ----------------
// users blocks: q_user -> vtB (V for news-direction), e_q_un -> eRowA, e_k_nu -> eColB
// news  blocks: k_news -> vtA (V for user-direction), e_k_un -> eColA, e_q_nu -> eRowB
// e layout: [b][h][r] (pre-scaled by log2 e).
// vt layout: [b][h][tile=c/32][hd][kk=c%32]  (2KB blocks; p2 B-frag reads are contiguous)
__global__ __launch_bounds__(256) void p1_kernel(
    const float* __restrict__ uf, const float* __restrict__ nf,
    const float* __restrict__ Wu, const float* __restrict__ Wn,
    const float* __restrict__ a_un, const float* __restrict__ a_nu,
    _Float16* __restrict__ vtA, _Float16* __restrict__ vtB,
    float* __restrict__ eRowA, float* __restrict__ eColA,
    float* __restrict__ eRowB, float* __restrict__ eColB)
{
  __shared__ float fs[64][132];    // feature tile, padded
  __shared__ float WsT[32][132];   // W transposed [k][d], padded
  __shared__ float qt[32][65];     // q tile transposed [k][u]
  __shared__ float aAs[32], aBs[32];

  const int bid = blockIdx.x;
  const int tid = threadIdx.x;

  int b, rt, R;
  const float *feat, *W;
  _Float16* vt;
  float *eA, *eB;
  int aAoff, aBoff;
  const float *avA, *avB;
  if (bid < 128) {                       // users
    b = bid >> 4; rt = bid & 15; R = U_;
    feat = uf; W = Wu; vt = vtB;
    eA = eRowA; eB = eColB;
    avA = a_un; aAoff = 0;  avB = a_nu; aBoff = HD;
  } else {                               // news
    int t2 = bid - 128;
    b = t2 >> 5; rt = t2 & 31; R = N_;
    feat = nf; W = Wn; vt = vtA;
    eA = eColA; eB = eRowB;
    avA = a_un; aAoff = HD; avB = a_nu; aBoff = 0;
  }
  const int r0 = rt * 64;
  const float4* feat4 = (const float4*)(feat + ((size_t)b * R + r0) * DIN);
  #pragma unroll
  for (int i = 0; i < 8; ++i) {
    int f4 = tid + 256 * i;              // 0..2047 float4s of the 64x128 tile
    int row = f4 >> 5, c4 = f4 & 31;
    *(float4*)&fs[row][c4 * 4] = feat4[row * 32 + c4];
  }

  const int kk = tid & 15, uu = tid >> 4;    // compute mapping: 2 k-cols x 4 u-rows
  const int u2 = tid & 63, part = tid >> 6;  // store/e mapping
  float eAv[H_], eBv[H_];

  #pragma unroll
  for (int h = 0; h < H_; ++h) {
    __syncthreads();
    {
      const float4* W4 = (const float4*)(W + (size_t)h * DIN * HD);
      #pragma unroll
      for (int i = 0; i < 4; ++i) {
        int f4 = tid + 256 * i;          // 0..1023
        int d = f4 >> 3, kc = f4 & 7;
        float4 v = W4[f4];
        WsT[kc * 4 + 0][d] = v.x;
        WsT[kc * 4 + 1][d] = v.y;
        WsT[kc * 4 + 2][d] = v.z;
        WsT[kc * 4 + 3][d] = v.w;
      }
      if (tid < 32) {
        aAs[tid] = avA[h * 64 + aAoff + tid];
        aBs[tid] = avB[h * 64 + aBoff + tid];
      }
    }
    __syncthreads();
    {
      float acc0[4] = {0.f, 0.f, 0.f, 0.f}, acc1[4] = {0.f, 0.f, 0.f, 0.f};
      #pragma unroll 8
      for (int d = 0; d < DIN; d += 4) {
        float4 w0 = *(const float4*)&WsT[kk][d];
        float4 w1 = *(const float4*)&WsT[kk + 16][d];
        #pragma unroll
        for (int i = 0; i < 4; ++i) {
          float4 fv = *(const float4*)&fs[uu + 16 * i][d];
          acc0[i] = fmaf(fv.x, w0.x, acc0[i]); acc0[i] = fmaf(fv.y, w0.y, acc0[i]);
          acc0[i] = fmaf(fv.z, w0.z, acc0[i]); acc0[i] = fmaf(fv.w, w0.w, acc0[i]);
          acc1[i] = fmaf(fv.x, w1.x, acc1[i]); acc1[i] = fmaf(fv.y, w1.y, acc1[i]);
          acc1[i] = fmaf(fv.z, w1.z, acc1[i]); acc1[i] = fmaf(fv.w, w1.w, acc1[i]);
        }
      }
      #pragma unroll
      for (int i = 0; i < 4; ++i) {
        qt[kk][uu + 16 * i] = acc0[i];
        qt[kk + 16][uu + 16 * i] = acc1[i];
      }
    }
    __syncthreads();
    {
      // vt store: c = r0+u2 -> tile (r0+u2)>>5, kk=(r0+u2)&31; element [tile][krow][kk]
      size_t vtbase = (size_t)(b * H_ + h) * (R * HD)
                    + (size_t)((r0 >> 5) + (u2 >> 5)) * (HD * 32) + (u2 & 31);
      #pragma unroll
      for (int jj = 0; jj < 8; ++jj) {
        int krow = part * 8 + jj;
        vt[vtbase + krow * 32] = (_Float16)qt[krow][u2];
      }
      float a_ = 0.f, b2_ = 0.f;
      #pragma unroll
      for (int k2 = 0; k2 < HD; ++k2) {
        float qv = qt[k2][u2];
        a_  = fmaf(qv, aAs[k2], a_);
        b2_ = fmaf(qv, aBs[k2], b2_);
      }
      eAv[h] = a_  * LOG2E;   // pre-scale by log2(e): exp(x) == exp2(x*LOG2E)
      eBv[h] = b2_ * LOG2E;
    }
  }
  if (part == 0) {
    #pragma unroll
    for (int h = 0; h < H_; ++h)
      eA[(size_t)(b * H_ + h) * R + r0 + u2] = eAv[h];
  } else if (part == 1) {
    #pragma unroll
    for (int h = 0; h < H_; ++h)
      eB[(size_t)(b * H_ + h) * R + r0 + u2] = eBv[h];
  }
}

// ---------------- phase 2 core: fused masked-softmax-weighted GEMM + epilogue ----------------
// One 16-row tile per block, wave = head. Adjacency strip staged once as an
// LDS bitmask via __ballot. Per col-tile per wave: 1 broadcast ds_read_b32 +
// 2 float4 e (broadcast) + 2 contiguous half8 vt -> 3 MFMAs (num x2 + ones-B den).
// Epilogue: accd[q] holds den[row] in every lane -> divide+bias+relu -> out directly.
template<int RR, int CC, int ROFF, int COFF, int PAD64>
__device__ __forceinline__ void p2_core(
    int b, int rt, int wave, int l,
    const int* __restrict__ adj, const _Float16* __restrict__ vt,
    const float* __restrict__ eRow, const float* __restrict__ eCol,
    const float* __restrict__ bias, float* __restrict__ out,
    unsigned long long* maskU)
{
  constexpr int CW64 = CC / 64;          // u64 words per mask row

  // ---- stage 16 x CC adjacency strip as bits (read once, coalesced) ----
  const int* adjBase = adj + (size_t)b * S_ * S_ + (size_t)(ROFF + rt * 16) * S_ + COFF;
  #pragma unroll 4
  for (int i = 0; i < (16 * CW64) / 4; ++i) {
    int f = i * 4 + wave;
    int row = f / CW64, chunk = f % CW64;
    int av = adjBase[(size_t)row * S_ + chunk * 64 + l];
    unsigned long long m = __ballot(av != 0);
    if (l == 0) maskU[row * PAD64 + chunk] = m;
  }
  __syncthreads();

  const int h = wave;
  const int row16 = l & 15;
  const int cg = (l >> 4) << 3;          // per-lane-group K offset within 32-col tile
  const int r = rt * 16 + row16;
  const float eq = eRow[(size_t)(b * H_ + h) * RR + r];
  const float* ecolH = eCol + (size_t)(b * H_ + h) * CC;
  const _Float16* vtb = vt + (size_t)(b * H_ + h) * (CC * HD);
  const unsigned int* maskW = (const unsigned int*)maskU;
  const int mrow = row16 * (PAD64 * 2);  // u32 words per row (padded)

  f32x4 acc0 = {0.f, 0.f, 0.f, 0.f}, acc1 = {0.f, 0.f, 0.f, 0.f}, accd = {0.f, 0.f, 0.f, 0.f};
  half8 ones = {(_Float16)1.f, (_Float16)1.f, (_Float16)1.f, (_Float16)1.f,
                (_Float16)1.f, (_Float16)1.f, (_Float16)1.f, (_Float16)1.f};

  #pragma unroll 2
  for (int t = 0; t < CC / 32; ++t) {
    const int cb = t * 32 + cg;
    unsigned int mb = maskW[mrow + t] >> cg;     // same-word broadcast across groups
    float4 e0 = *(const float4*)(ecolH + cb);
    float4 e1 = *(const float4*)(ecolH + cb + 4);
    float ecv[8] = {e0.x, e0.y, e0.z, e0.w, e1.x, e1.y, e1.z, e1.w};
    float wv[8];
    #pragma unroll
    for (int j = 0; j < 8; ++j) {
      float s  = eq + ecv[j];                 // already log2e-scaled
      float ls = fmaxf(s, 0.2f * s);          // leaky (positive scale commutes)
      ls = (mb & (1u << j)) ? ls : -1e9f;     // masked -> exp2 underflows to exact 0
      wv[j] = exp2f(ls);
    }
    union { fp16x2 h2[4]; half8 h8; } uw;
    #pragma unroll
    for (int j = 0; j < 4; ++j)
      uw.h2[j] = __builtin_amdgcn_cvt_pkrtz(wv[2 * j], wv[2 * j + 1]);
    half8 w = uw.h8;
    // tile-interleaved V: [t][hd][kk] -> wave reads 2x1KB contiguous
    const half8 b0 = *(const half8*)(vtb + t * (HD * 32) + row16 * 32 + cg);
    const half8 b1 = *(const half8*)(vtb + t * (HD * 32) + (row16 + 16) * 32 + cg);
    acc0 = __builtin_amdgcn_mfma_f32_16x16x32_f16(w, b0, acc0, 0, 0, 0);
    acc1 = __builtin_amdgcn_mfma_f32_16x16x32_f16(w, b1, acc1, 0, 0, 0);
    accd = __builtin_amdgcn_mfma_f32_16x16x32_f16(w, ones, accd, 0, 0, 0);
  }

  // ---- fused epilogue: divide, bias, relu, store ----
  const int colk = row16;
  const int rowbase = rt * 16 + ((l >> 4) << 2);
  #pragma unroll
  for (int q = 0; q < 4; ++q) {
    int orow = rowbase + q;                  // C layout: col=l&15, row=(l>>4)*4+q
    size_t o = ((size_t)(b * H_ + h) * RR + orow) * 32 + colk;
    float den = accd[q];                     // den[row] replicated across cols
    float v0 = acc0[q] / den + bias[q * 32 + colk];
    float v1 = acc1[q] / den + bias[q * 32 + colk + 16];
    out[o]      = v0 > 0.f ? v0 : 0.f;
    out[o + 16] = v1 > 0.f ? v1 : 0.f;
  }
}

// Both directions in ONE grid: bid 0..511 = direction A (rows=users),
// bid 512..1535 = direction B (rows=news). Whole-block-uniform branch.
// launch_bounds(256,4): VGPR cap 128 — the previous (256,6) capped at ~85
// and forced scratch spills in the inner loop (round-2 profile: VGPR_Count=64
// with 48+ regs of live accumulators).
__global__ __launch_bounds__(256, 4) void p2_kernel(
    const int* __restrict__ adj,
    const _Float16* __restrict__ vtA, const _Float16* __restrict__ vtB,
    const float* __restrict__ eRowA, const float* __restrict__ eColA,
    const float* __restrict__ eRowB, const float* __restrict__ eColB,
    const float* __restrict__ bu, const float* __restrict__ bn,
    float* __restrict__ out)
{
  __shared__ unsigned long long maskU[16 * 33];   // max of the two instantiations
  const int tid = threadIdx.x;
  const int wave = tid >> 6, l = tid & 63;
  const int bid = blockIdx.x;
  if (bid < B_ * (U_ / 16)) {
    const int b = bid >> 6, rt = bid & 63;
    p2_core<U_, N_, 0, U_, 33>(b, rt, wave, l, adj, vtA, eRowA, eColA, bu,
                               out, maskU);
  } else {
    const int t2 = bid - B_ * (U_ / 16);
    const int b = t2 >> 7, rt = t2 & 127;
    p2_core<N_, U_, U_, 0, 17>(b, rt, wave, l, adj, vtB, eRowB, eColB, bn,
                               out + (size_t)B_ * U_ * 128, maskU);
  }
}

extern "C" void kernel_launch(void* const* d_in, const int* in_sizes, int n_in,
                              void* d_out, int out_size, void* d_ws, size_t ws_size,
                              hipStream_t stream) {
  const float* uf  = (const float*)d_in[0];
  const float* nf  = (const float*)d_in[1];
  const int*   adj = (const int*)d_in[2];
  const float* Wu  = (const float*)d_in[3];
  const float* Wn  = (const float*)d_in[4];
  const float* aun = (const float*)d_in[5];
  const float* anu = (const float*)d_in[6];
  const float* bu  = (const float*)d_in[7];
  const float* bn  = (const float*)d_in[8];

  char* ws = (char*)d_ws;
  size_t off = 0;
  _Float16* vtA = (_Float16*)(ws + off); off += (size_t)B_ * H_ * HD * N_ * 2;  // 4 MB
  _Float16* vtB = (_Float16*)(ws + off); off += (size_t)B_ * H_ * HD * U_ * 2;  // 2 MB
  float* eRowA = (float*)(ws + off); off += (size_t)B_ * H_ * U_ * 4;
  float* eColA = (float*)(ws + off); off += (size_t)B_ * H_ * N_ * 4;
  float* eRowB = (float*)(ws + off); off += (size_t)B_ * H_ * N_ * 4;
  float* eColB = (float*)(ws + off); off += (size_t)B_ * H_ * U_ * 4;
  (void)off; (void)ws_size; (void)in_sizes; (void)n_in; (void)out_size;        // ~7.7 MB total

  p1_kernel<<<384, 256, 0, stream>>>(uf, nf, Wu, Wn, aun, anu,
                                     vtA, vtB, eRowA, eColA, eRowB, eColB);
  p2_kernel<<<B_ * (U_ / 16) + B_ * (N_ / 16), 256, 0, stream>>>(
      adj, vtA, vtB, eRowA, eColA, eRowB, eColB, bu, bn, (float*)d_out);
}

// Round 8
// 119.264 us; speedup vs baseline: 1.5438x; 1.0198x over previous
//
#include <hip/hip_runtime.h>
#include <hip/hip_bf16.h>

typedef _Float16 half8 __attribute__((ext_vector_type(8)));
typedef __fp16 fp16x2 __attribute__((ext_vector_type(2)));
typedef float f32x4 __attribute__((ext_vector_type(4)));

#define B_ 8
#define U_ 1024
#define N_ 2048
#define DIN 128
#define H_ 4
#define HD 32
#define S_ 3072
#define LOG2E 1.44269504f

// ---------------- phase 1: projections + e-vectors + tiled f16 V ----------------
// users blocks: q_user -> vtB (V for news-direction), e_q_un -> eRowA, e_k_nu -> eColB
// news  blocks: k_news -> vtA (V for user-direction), e_k_un -> eColA, e_q_nu -> eRowB
// e layout: [b][h][r] (pre-scaled by log2 e).
// vt layout: [b][h][tile=c/32][hd][kk=c%32]  (2KB blocks; p2 B-frag reads are contiguous)
__global__ __launch_bounds__(256) void p1_kernel(
    const float* __restrict__ uf, const float* __restrict__ nf,
    const float* __restrict__ Wu, const float* __restrict__ Wn,
    const float* __restrict__ a_un, const float* __restrict__ a_nu,
    _Float16* __restrict__ vtA, _Float16* __restrict__ vtB,
    float* __restrict__ eRowA, float* __restrict__ eColA,
    float* __restrict__ eRowB, float* __restrict__ eColB)
{
  __shared__ float fs[64][132];    // feature tile, padded
  __shared__ float WsT[32][132];   // W transposed [k][d], padded
  __shared__ float qt[32][65];     // q tile transposed [k][u]
  __shared__ float aAs[32], aBs[32];

  const int bid = blockIdx.x;
  const int tid = threadIdx.x;

  int b, rt, R;
  const float *feat, *W;
  _Float16* vt;
  float *eA, *eB;
  int aAoff, aBoff;
  const float *avA, *avB;
  if (bid < 128) {                       // users
    b = bid >> 4; rt = bid & 15; R = U_;
    feat = uf; W = Wu; vt = vtB;
    eA = eRowA; eB = eColB;
    avA = a_un; aAoff = 0;  avB = a_nu; aBoff = HD;
  } else {                               // news
    int t2 = bid - 128;
    b = t2 >> 5; rt = t2 & 31; R = N_;
    feat = nf; W = Wn; vt = vtA;
    eA = eColA; eB = eRowB;
    avA = a_un; aAoff = HD; avB = a_nu; aBoff = 0;
  }
  const int r0 = rt * 64;
  const float4* feat4 = (const float4*)(feat + ((size_t)b * R + r0) * DIN);
  #pragma unroll
  for (int i = 0; i < 8; ++i) {
    int f4 = tid + 256 * i;              // 0..2047 float4s of the 64x128 tile
    int row = f4 >> 5, c4 = f4 & 31;
    *(float4*)&fs[row][c4 * 4] = feat4[row * 32 + c4];
  }

  const int kk = tid & 15, uu = tid >> 4;    // compute mapping: 2 k-cols x 4 u-rows
  const int u2 = tid & 63, part = tid >> 6;  // store/e mapping
  float eAv[H_], eBv[H_];

  #pragma unroll
  for (int h = 0; h < H_; ++h) {
    __syncthreads();
    {
      const float4* W4 = (const float4*)(W + (size_t)h * DIN * HD);
      #pragma unroll
      for (int i = 0; i < 4; ++i) {
        int f4 = tid + 256 * i;          // 0..1023
        int d = f4 >> 3, kc = f4 & 7;
        float4 v = W4[f4];
        WsT[kc * 4 + 0][d] = v.x;
        WsT[kc * 4 + 1][d] = v.y;
        WsT[kc * 4 + 2][d] = v.z;
        WsT[kc * 4 + 3][d] = v.w;
      }
      if (tid < 32) {
        aAs[tid] = avA[h * 64 + aAoff + tid];
        aBs[tid] = avB[h * 64 + aBoff + tid];
      }
    }
    __syncthreads();
    {
      float acc0[4] = {0.f, 0.f, 0.f, 0.f}, acc1[4] = {0.f, 0.f, 0.f, 0.f};
      #pragma unroll 8
      for (int d = 0; d < DIN; d += 4) {
        float4 w0 = *(const float4*)&WsT[kk][d];
        float4 w1 = *(const float4*)&WsT[kk + 16][d];
        #pragma unroll
        for (int i = 0; i < 4; ++i) {
          float4 fv = *(const float4*)&fs[uu + 16 * i][d];
          acc0[i] = fmaf(fv.x, w0.x, acc0[i]); acc0[i] = fmaf(fv.y, w0.y, acc0[i]);
          acc0[i] = fmaf(fv.z, w0.z, acc0[i]); acc0[i] = fmaf(fv.w, w0.w, acc0[i]);
          acc1[i] = fmaf(fv.x, w1.x, acc1[i]); acc1[i] = fmaf(fv.y, w1.y, acc1[i]);
          acc1[i] = fmaf(fv.z, w1.z, acc1[i]); acc1[i] = fmaf(fv.w, w1.w, acc1[i]);
        }
      }
      #pragma unroll
      for (int i = 0; i < 4; ++i) {
        qt[kk][uu + 16 * i] = acc0[i];
        qt[kk + 16][uu + 16 * i] = acc1[i];
      }
    }
    __syncthreads();
    {
      // vt store: c = r0+u2 -> tile (r0+u2)>>5, kk=(r0+u2)&31; element [tile][krow][kk]
      size_t vtbase = (size_t)(b * H_ + h) * (R * HD)
                    + (size_t)((r0 >> 5) + (u2 >> 5)) * (HD * 32) + (u2 & 31);
      #pragma unroll
      for (int jj = 0; jj < 8; ++jj) {
        int krow = part * 8 + jj;
        vt[vtbase + krow * 32] = (_Float16)qt[krow][u2];
      }
      float a_ = 0.f, b2_ = 0.f;
      #pragma unroll
      for (int k2 = 0; k2 < HD; ++k2) {
        float qv = qt[k2][u2];
        a_  = fmaf(qv, aAs[k2], a_);
        b2_ = fmaf(qv, aBs[k2], b2_);
      }
      eAv[h] = a_  * LOG2E;   // pre-scale by log2(e): exp(x) == exp2(x*LOG2E)
      eBv[h] = b2_ * LOG2E;
    }
  }
  if (part == 0) {
    #pragma unroll
    for (int h = 0; h < H_; ++h)
      eA[(size_t)(b * H_ + h) * R + r0 + u2] = eAv[h];
  } else if (part == 1) {
    #pragma unroll
    for (int h = 0; h < H_; ++h)
      eB[(size_t)(b * H_ + h) * R + r0 + u2] = eBv[h];
  }
}

// ---------------- phase 2 core: fused masked-softmax-weighted GEMM + epilogue ----------------
// One 16-row tile per block, wave = head. Adjacency strip staged once as an
// LDS bitmask via __ballot. Per col-tile per wave: 1 broadcast ds_read_b32 +
// 2 float4 e (broadcast) + 2 contiguous half8 vt -> 3 MFMAs (num x2 + ones-B den).
// Epilogue: accd[q] holds den[row] in every lane -> divide+bias+relu -> out directly.
template<int RR, int CC, int ROFF, int COFF, int PAD64>
__device__ __forceinline__ void p2_core(
    int b, int rt, int wave, int l,
    const int* __restrict__ adj, const _Float16* __restrict__ vt,
    const float* __restrict__ eRow, const float* __restrict__ eCol,
    const float* __restrict__ bias, float* __restrict__ out,
    unsigned long long* maskU)
{
  constexpr int CW64 = CC / 64;          // u64 words per mask row

  // ---- stage 16 x CC adjacency strip as bits (read once, coalesced) ----
  const int* adjBase = adj + (size_t)b * S_ * S_ + (size_t)(ROFF + rt * 16) * S_ + COFF;
  #pragma unroll 4
  for (int i = 0; i < (16 * CW64) / 4; ++i) {
    int f = i * 4 + wave;
    int row = f / CW64, chunk = f % CW64;
    int av = adjBase[(size_t)row * S_ + chunk * 64 + l];
    unsigned long long m = __ballot(av != 0);
    if (l == 0) maskU[row * PAD64 + chunk] = m;
  }
  __syncthreads();

  const int h = wave;
  const int row16 = l & 15;
  const int cg = (l >> 4) << 3;          // per-lane-group K offset within 32-col tile
  const int r = rt * 16 + row16;
  const float eq = eRow[(size_t)(b * H_ + h) * RR + r];
  const float* ecolH = eCol + (size_t)(b * H_ + h) * CC;
  const _Float16* vtb = vt + (size_t)(b * H_ + h) * (CC * HD);
  const unsigned int* maskW = (const unsigned int*)maskU;
  const int mrow = row16 * (PAD64 * 2);  // u32 words per row (padded)

  f32x4 acc0 = {0.f, 0.f, 0.f, 0.f}, acc1 = {0.f, 0.f, 0.f, 0.f}, accd = {0.f, 0.f, 0.f, 0.f};
  half8 ones = {(_Float16)1.f, (_Float16)1.f, (_Float16)1.f, (_Float16)1.f,
                (_Float16)1.f, (_Float16)1.f, (_Float16)1.f, (_Float16)1.f};

  #pragma unroll 2
  for (int t = 0; t < CC / 32; ++t) {
    const int cb = t * 32 + cg;
    unsigned int mb = maskW[mrow + t] >> cg;     // same-word broadcast across groups
    float4 e0 = *(const float4*)(ecolH + cb);
    float4 e1 = *(const float4*)(ecolH + cb + 4);
    float ecv[8] = {e0.x, e0.y, e0.z, e0.w, e1.x, e1.y, e1.z, e1.w};
    float wv[8];
    #pragma unroll
    for (int j = 0; j < 8; ++j) {
      float s  = eq + ecv[j];                 // already log2e-scaled
      float ls = fmaxf(s, 0.2f * s);          // leaky (positive scale commutes)
      ls = (mb & (1u << j)) ? ls : -1e9f;     // masked -> exp2 underflows to exact 0
      wv[j] = exp2f(ls);
    }
    union { fp16x2 h2[4]; half8 h8; } uw;
    #pragma unroll
    for (int j = 0; j < 4; ++j)
      uw.h2[j] = __builtin_amdgcn_cvt_pkrtz(wv[2 * j], wv[2 * j + 1]);
    half8 w = uw.h8;
    // tile-interleaved V: [t][hd][kk] -> wave reads 2x1KB contiguous
    const half8 b0 = *(const half8*)(vtb + t * (HD * 32) + row16 * 32 + cg);
    const half8 b1 = *(const half8*)(vtb + t * (HD * 32) + (row16 + 16) * 32 + cg);
    acc0 = __builtin_amdgcn_mfma_f32_16x16x32_f16(w, b0, acc0, 0, 0, 0);
    acc1 = __builtin_amdgcn_mfma_f32_16x16x32_f16(w, b1, acc1, 0, 0, 0);
    accd = __builtin_amdgcn_mfma_f32_16x16x32_f16(w, ones, accd, 0, 0, 0);
  }

  // ---- fused epilogue: divide, bias, relu, store ----
  const int colk = row16;
  const int rowbase = rt * 16 + ((l >> 4) << 2);
  #pragma unroll
  for (int q = 0; q < 4; ++q) {
    int orow = rowbase + q;                  // C layout: col=l&15, row=(l>>4)*4+q
    size_t o = ((size_t)(b * H_ + h) * RR + orow) * 32 + colk;
    float den = accd[q];                     // den[row] replicated across cols
    float v0 = acc0[q] / den + bias[q * 32 + colk];
    float v1 = acc1[q] / den + bias[q * 32 + colk + 16];
    out[o]      = v0 > 0.f ? v0 : 0.f;
    out[o + 16] = v1 > 0.f ? v1 : 0.f;
  }
}

// Both directions in ONE grid. XCD-aware decode: b = bid & 7 so all blocks of
// batch b land on XCD b (default assignment is round-robin bid%8). Per-XCD L2
// working set becomes vtA[b]+vtB[b]+e[b] ~ 0.8MB -> vt reads L2-resident
// instead of thrashing (previous decode spread every batch over every XCD:
// 6MB vt + 134MB adjacency streaming through each 4MB L2).
__global__ __launch_bounds__(256, 4) void p2_kernel(
    const int* __restrict__ adj,
    const _Float16* __restrict__ vtA, const _Float16* __restrict__ vtB,
    const float* __restrict__ eRowA, const float* __restrict__ eColA,
    const float* __restrict__ eRowB, const float* __restrict__ eColB,
    const float* __restrict__ bu, const float* __restrict__ bn,
    float* __restrict__ out)
{
  __shared__ unsigned long long maskU[16 * 33];   // max of the two instantiations
  const int tid = threadIdx.x;
  const int wave = tid >> 6, l = tid & 63;
  const int bid = blockIdx.x;
  if (bid < B_ * (U_ / 16)) {
    const int b = bid & 7, rt = bid >> 3;         // rt 0..63
    p2_core<U_, N_, 0, U_, 33>(b, rt, wave, l, adj, vtA, eRowA, eColA, bu,
                               out, maskU);
  } else {
    const int t2 = bid - B_ * (U_ / 16);
    const int b = t2 & 7, rt = t2 >> 3;           // rt 0..127
    p2_core<N_, U_, U_, 0, 17>(b, rt, wave, l, adj, vtB, eRowB, eColB, bn,
                               out + (size_t)B_ * U_ * 128, maskU);
  }
}

extern "C" void kernel_launch(void* const* d_in, const int* in_sizes, int n_in,
                              void* d_out, int out_size, void* d_ws, size_t ws_size,
                              hipStream_t stream) {
  const float* uf  = (const float*)d_in[0];
  const float* nf  = (const float*)d_in[1];
  const int*   adj = (const int*)d_in[2];
  const float* Wu  = (const float*)d_in[3];
  const float* Wn  = (const float*)d_in[4];
  const float* aun = (const float*)d_in[5];
  const float* anu = (const float*)d_in[6];
  const float* bu  = (const float*)d_in[7];
  const float* bn  = (const float*)d_in[8];

  char* ws = (char*)d_ws;
  size_t off = 0;
  _Float16* vtA = (_Float16*)(ws + off); off += (size_t)B_ * H_ * HD * N_ * 2;  // 4 MB
  _Float16* vtB = (_Float16*)(ws + off); off += (size_t)B_ * H_ * HD * U_ * 2;  // 2 MB
  float* eRowA = (float*)(ws + off); off += (size_t)B_ * H_ * U_ * 4;
  float* eColA = (float*)(ws + off); off += (size_t)B_ * H_ * N_ * 4;
  float* eRowB = (float*)(ws + off); off += (size_t)B_ * H_ * N_ * 4;
  float* eColB = (float*)(ws + off); off += (size_t)B_ * H_ * U_ * 4;
  (void)off; (void)ws_size; (void)in_sizes; (void)n_in; (void)out_size;        // ~7.7 MB total

  p1_kernel<<<384, 256, 0, stream>>>(uf, nf, Wu, Wn, aun, anu,
                                     vtA, vtB, eRowA, eColA, eRowB, eColB);
  p2_kernel<<<B_ * (U_ / 16) + B_ * (N_ / 16), 256, 0, stream>>>(
      adj, vtA, vtB, eRowA, eColA, eRowB, eColB, bu, bn, (float*)d_out);
}